// Round 11
// baseline (430.718 us; speedup 1.0000x reference)
//
#include <hip/hip_runtime.h>
#include <math.h>

// Problem constants
#define NB   2048
#define NFC  171
#define NFR  171
#define NL   32
#define NH   256
#define NE   16
#define NGH  64
#define NIN  203   /* L + FC */
#define NINT 288   /* L + H  */
#define NOUT 171

typedef __attribute__((ext_vector_type(8))) short bf16x8;   // 8 bf16 in 4 VGPRs
typedef __attribute__((ext_vector_type(4))) float f32x4;    // MFMA acc

__device__ __forceinline__ float elu_f(float v) {
    return v > 0.0f ? v : expm1f(v);
}

// f32 -> bf16 bits, round-to-nearest-even
__device__ __forceinline__ short f2bf(float f) {
    unsigned u = __float_as_uint(f);
    unsigned r = (u + 0x7FFFu + ((u >> 16) & 1u)) >> 16;
    return (short)r;
}

// async global->LDS, 16 bytes per lane; lds base must be wave-uniform
__device__ __forceinline__ void gload16(void* lds, const void* g) {
    __builtin_amdgcn_global_load_lds(
        (const __attribute__((address_space(1))) unsigned*)g,
        (__attribute__((address_space(3))) unsigned*)lds, 16, 0, 0);
}

template<int N> __device__ __forceinline__ void waitcnt_vm() {
    if constexpr (N == 0)      asm volatile("s_waitcnt vmcnt(0) lgkmcnt(0)" ::: "memory");
    else if constexpr (N == 1) asm volatile("s_waitcnt vmcnt(1) lgkmcnt(0)" ::: "memory");
    else if constexpr (N == 2) asm volatile("s_waitcnt vmcnt(2) lgkmcnt(0)" ::: "memory");
    else if constexpr (N == 3) asm volatile("s_waitcnt vmcnt(3) lgkmcnt(0)" ::: "memory");
    else                       asm volatile("s_waitcnt vmcnt(4) lgkmcnt(0)" ::: "memory");
}
// BK=64 path (enc/mulvz): 2 loads per B-stage, 4 buffers
__device__ __forceinline__ void loop_sync64(int s, int NS) {
    if (s + 3 < NS)      waitcnt_vm<4>();
    else if (s + 2 < NS) waitcnt_vm<2>();
    else                 waitcnt_vm<0>();
    __builtin_amdgcn_s_barrier();
}
// MoE 2-step phase: rem = steps not yet consumed after this phase
__device__ __forceinline__ void phase_sync(int rem) {
    if (rem >= 6)      waitcnt_vm<4>();
    else if (rem == 5) waitcnt_vm<3>();
    else if (rem == 4) waitcnt_vm<2>();
    else if (rem == 3) waitcnt_vm<1>();
    else               waitcnt_vm<0>();
    __builtin_amdgcn_s_barrier();
}

// ---------------------------------------------------------------------------
// prep_all: blocks [0,3168) = weight transpose tiles; [3168, 3168+2048) = panels
// Also zeroes the MoE tile-completion counters (block 0).
// ---------------------------------------------------------------------------
__global__ __launch_bounds__(256) void prep_all(
    const float* s0, const float* s1, const float* s2, const float* s3,
    const float* s4, const float* s5, const float* s6,
    const float* s7, const float* s8, const float* s9,
    short* d0, short* d1, short* d2, short* d3,
    short* d4, short* d5, short* d6, short* d7, short* d8, short* d9,
    const float* __restrict__ x, const float* __restrict__ c,
    short* __restrict__ xc, short* __restrict__ xh1, short* __restrict__ xh2,
    short* __restrict__ inp0, int* __restrict__ cnts)
{
    __shared__ float T[32][33];
    const int tid = threadIdx.x;

    if (blockIdx.x == 0) {
        for (int i = tid; i < 384; i += 256) cnts[i] = 0;
    }

    if (blockIdx.x >= 3168) {
        // ---- input panels, one block per batch row ----
        const int b = blockIdx.x - 3168;
        for (int i = tid; i < 384; i += 256) {
            float v = (i < 171) ? x[b * 171 + i] : ((i < 342) ? c[b * 171 + (i - 171)] : 0.0f);
            xc[(size_t)b * 384 + i] = f2bf(v);
        }
        for (int i = tid; i < 171; i += 256) {
            short v = f2bf(x[b * 171 + i]);
            xh1[(size_t)b * 448 + i] = v;
            xh2[(size_t)b * 448 + i] = v;
        }
        for (int i = tid; i < 21; i += 256) {
            xh1[(size_t)b * 448 + 427 + i] = 0;
            xh2[(size_t)b * 448 + 427 + i] = 0;
        }
        for (int i = tid; i < 192; i += 256) {
            inp0[(size_t)b * 224 + 32 + i] = (i < 171) ? f2bf(c[b * 171 + i]) : (short)0;
        }
        return;
    }

    // ---- weight transpose tiles (10 segments) ----
    constexpr int K_[10]   = {342, 427, 427, 427, 203, 288, 288, 203,  64,  64};
    constexpr int O_[10]   = {256, 256,  32,  32, 256, 256, 171,  64,  64,  16};
    constexpr int KP_[10]  = {384, 448, 448, 448, 224, 288, 288, 224,  64,  64};
    constexpr int OP_[10]  = {256, 256,  64,  64, 256, 256, 192,  64,  64,  32};
    constexpr int nKT_[10] = { 12,  14,  14,  14,   7,   9,   9,   7,   2,   2};
    constexpr int tpe_[10] = { 96, 112,  14,  14,  56,  72,  54,  14,   4,   2};
    constexpr int st_[10]  = {  0,  96, 208, 222, 236,1132,2284,3148,3162,3166};
    const float* srcs[10] = {s0, s1, s2, s3, s4, s5, s6, s7, s8, s9};
    short*       dsts[10] = {d0, d1, d2, d3, d4, d5, d6, d7, d8, d9};

    int t = blockIdx.x;
    int s = 0;
    while (s < 9 && t >= st_[s + 1]) ++s;
    int local = t - st_[s];
    int e = local / tpe_[s];
    int rem = local - e * tpe_[s];
    int ox = rem / nKT_[s];
    int ky = rem - ox * nKT_[s];
    const int K = K_[s], O = O_[s], KP = KP_[s], OP = OP_[s];
    const float* src = srcs[s];
    short* dst = dsts[s];

    const int cc = tid & 31, r0 = tid >> 5;
#pragma unroll
    for (int i = 0; i < 4; ++i) {
        int r = r0 + i * 8;
        int gk = ky * 32 + r, go = ox * 32 + cc;
        T[r][cc] = (gk < K && go < O) ? src[((size_t)e * K + gk) * O + go] : 0.0f;
    }
    __syncthreads();
#pragma unroll
    for (int i = 0; i < 4; ++i) {
        int r = r0 + i * 8;
        int go = ox * 32 + r, gk = ky * 32 + cc;
        dst[((size_t)e * OP + go) * KP + gk] = f2bf(T[cc][r]);
    }
}

// ---------------------------------------------------------------------------
// enc_gemm: BM=32, BN=64, BK=64.  grid (NO/64, 64)   (verified R5)
// ---------------------------------------------------------------------------
template<int KP>
__global__ __launch_bounds__(256, 2) void enc_gemm(
    const short* __restrict__ A,
    const short* __restrict__ Wt,
    const float* __restrict__ bias,
    short* __restrict__ dst, int dstld, int dstoff)
{
    constexpr int NKS = KP / 64;
    constexpr int CHR = KP / 8;

    __shared__ short As[32 * KP];
    __shared__ short Bs[4][64 * 64];

    const int tid = threadIdx.x;
    const int lane = tid & 63;
    const int wid = tid >> 6;
    const int wm = wid & 1, wn = wid >> 1;
    const int brow = blockIdx.y * 32, bcol = blockIdx.x * 64;
    const int wbase = wid * 1024;
    const int kseg = lane >> 4;

#pragma unroll
    for (int i = 0; i < (32 * CHR) / 256; ++i) {
        int ch = i * 256 + tid;
        int r = ch / CHR, kc = ch - r * CHR;
        int kcs = kc ^ ((r >> 1) & 3);
        gload16((char*)As + i * 4096 + wbase, A + (size_t)(brow + r) * KP + kcs * 8);
    }
    auto stageB = [&](int buf, int ks) {
#pragma unroll
        for (int g = 0; g < 2; ++g) {
            int ch = g * 256 + tid;
            int o = ch >> 3, sl = ch & 7;
            int sp = sl ^ ((o >> 1) & 3);
            gload16((char*)Bs[buf] + g * 4096 + wbase,
                    Wt + (size_t)(bcol + o) * KP + ks * 64 + sp * 8);
        }
    };
    stageB(0, 0); stageB(1, 1); stageB(2, 2);
    waitcnt_vm<4>();
    __builtin_amdgcn_s_barrier();

    const f32x4 zero4 = {0.0f, 0.0f, 0.0f, 0.0f};
    f32x4 acc[2] = {zero4, zero4};

    for (int s = 0; s < NKS; ++s) {
        if (s + 3 < NKS) stageB((s + 3) & 3, s + 3);
#pragma unroll
        for (int kk = 0; kk < 2; ++kk) {
            bf16x8 a, b[2];
            int rr = wm * 16 + (lane & 15);
            int kcp = (s * 8 + kk * 4 + kseg) ^ ((rr >> 1) & 3);
            a = *(const bf16x8*)&As[rr * KP + kcp * 8];
#pragma unroll
            for (int nr = 0; nr < 2; ++nr) {
                int oo = wn * 32 + nr * 16 + (lane & 15);
                int sp = (kk * 4 + kseg) ^ ((oo >> 1) & 3);
                b[nr] = *(const bf16x8*)&Bs[s & 3][oo * 64 + sp * 8];
            }
#pragma unroll
            for (int nr = 0; nr < 2; ++nr)
                acc[nr] = __builtin_amdgcn_mfma_f32_16x16x32_bf16(a, b[nr], acc[nr], 0, 0, 0);
        }
        loop_sync64(s, NKS);
    }

#pragma unroll
    for (int j = 0; j < 4; ++j) {
        int row = brow + wm * 16 + kseg * 4 + j;
#pragma unroll
        for (int nr = 0; nr < 2; ++nr) {
            int col = bcol + wn * 32 + nr * 16 + (lane & 15);
            float v = acc[nr][j] + bias[col];
            dst[(size_t)row * dstld + dstoff + col] = f2bf(elu_f(v));
        }
    }
}

// ---------------------------------------------------------------------------
// mulvz_gate: BM=32, grid (1,64).  (verified R5)
// ---------------------------------------------------------------------------
__global__ __launch_bounds__(256) void mulvz_gate(
    const short* __restrict__ A,             // xh2 [2048][448]
    const short* __restrict__ Wt,            // mlWt [64][448]
    const float* __restrict__ mub, const float* __restrict__ lvb,
    const float* __restrict__ eps,
    const short* __restrict__ g0wt,          // [64][224]
    const short* __restrict__ g1wt,          // [64][64]
    const short* __restrict__ g2wt,          // [32][64] rows 16..31 zero
    const float* __restrict__ g0b, const float* __restrict__ g1b,
    const float* __restrict__ g2b,
    float* __restrict__ mu_out, float* __restrict__ lv_out,
    short* __restrict__ inp0, short* __restrict__ inp1, short* __restrict__ inp2,
    float* __restrict__ coef)
{
    constexpr int KP = 448;
    constexpr int NKS = KP / 64;   // 7
    constexpr int CHR = KP / 8;    // 56

    __shared__ short As[32 * 448];
    __shared__ short Bs[4][64 * 64];
    __shared__ float Els[32][32];
    __shared__ short gA[32 * 224];
    __shared__ short g0s[64 * 224];
    __shared__ short g1s[64 * 64];
    __shared__ short g2s[32 * 64];
    __shared__ short hA[32 * 64];
    __shared__ short hB[32 * 64];

    const int tid = threadIdx.x;
    const int lane = tid & 63;
    const int wid = tid >> 6;
    const int wm = wid & 1, wn = wid >> 1;
    const int brow = blockIdx.y * 32;
    const int wbase = wid * 1024;
    const int kseg = lane >> 4;
    const int l15 = lane & 15;

    // ---- A panel (7 gloads) ----
#pragma unroll
    for (int i = 0; i < 7; ++i) {
        int ch = i * 256 + tid;
        int r = ch / CHR, kc = ch - r * CHR;
        int kcs = kc ^ ((r >> 1) & 3);
        gload16((char*)As + i * 4096 + wbase, A + (size_t)(brow + r) * KP + kcs * 8);
    }
    // ---- gate A panel c-part from inp0 ----
#pragma unroll
    for (int i = 0; i < 4; ++i) {
        int ch = i * 256 + tid;
        if (ch < 896) {
            int r = ch / 28, kc = ch - r * 28;
            int kcs = kc ^ ((r >> 1) & 3);
            gload16((char*)gA + i * 4096 + wbase, inp0 + (size_t)(brow + r) * 224 + kcs * 8);
        }
    }
    // ---- gate weights ----
#pragma unroll
    for (int i = 0; i < 7; ++i) {
        int ch = i * 256 + tid;
        int r = ch / 28, kc = ch - r * 28;
        int kcs = kc ^ ((r >> 1) & 3);
        gload16((char*)g0s + i * 4096 + wbase, g0wt + (size_t)r * 224 + kcs * 8);
    }
#pragma unroll
    for (int i = 0; i < 2; ++i) {
        int ch = i * 256 + tid;
        int r = ch >> 3, kc = ch & 7;
        int kcs = kc ^ ((r >> 1) & 3);
        gload16((char*)g1s + i * 4096 + wbase, g1wt + (size_t)r * 64 + kcs * 8);
    }
    {
        int ch = tid;
        int r = ch >> 3, kc = ch & 7;
        int kcs = kc ^ ((r >> 1) & 3);
        gload16((char*)g2s + wbase, g2wt + (size_t)r * 64 + kcs * 8);
    }
    // ---- B double-buffer ----
    auto stageB = [&](int buf, int ks) {
#pragma unroll
        for (int g = 0; g < 2; ++g) {
            int ch = g * 256 + tid;
            int o = ch >> 3, sl = ch & 7;
            int sp = sl ^ ((o >> 1) & 3);
            gload16((char*)Bs[buf] + g * 4096 + wbase,
                    Wt + (size_t)o * KP + ks * 64 + sp * 8);
        }
    };
    stageB(0, 0); stageB(1, 1); stageB(2, 2);
    waitcnt_vm<4>();
    __builtin_amdgcn_s_barrier();

    const f32x4 zero4 = {0.0f, 0.0f, 0.0f, 0.0f};
    f32x4 acc[2] = {zero4, zero4};

    for (int s = 0; s < NKS; ++s) {
        if (s + 3 < NKS) stageB((s + 3) & 3, s + 3);
#pragma unroll
        for (int kk = 0; kk < 2; ++kk) {
            bf16x8 av, b[2];
            int rr = wm * 16 + l15;
            int kcp = (s * 8 + kk * 4 + kseg) ^ ((rr >> 1) & 3);
            av = *(const bf16x8*)&As[rr * KP + kcp * 8];
#pragma unroll
            for (int nr = 0; nr < 2; ++nr) {
                int oo = wn * 32 + nr * 16 + l15;
                int sp = (kk * 4 + kseg) ^ ((oo >> 1) & 3);
                b[nr] = *(const bf16x8*)&Bs[s & 3][oo * 64 + sp * 8];
            }
#pragma unroll
            for (int nr = 0; nr < 2; ++nr)
                acc[nr] = __builtin_amdgcn_mfma_f32_16x16x32_bf16(av, b[nr], acc[nr], 0, 0, 0);
        }
        loop_sync64(s, NKS);
    }

    // ---- mu / lv epilogue ----
#pragma unroll
    for (int j = 0; j < 4; ++j) {
        int rl = wm * 16 + kseg * 4 + j;
        int row = brow + rl;
#pragma unroll
        for (int nr = 0; nr < 2; ++nr) {
            int cc = nr * 16 + l15;              // 0..31
            if (wn == 1) {
                float v = acc[nr][j] + lvb[cc];
                lv_out[(size_t)row * 32 + cc] = v;
                Els[rl][cc] = expf(0.5f * v);
            } else {
                float v = acc[nr][j] + mub[cc];
                mu_out[(size_t)row * 32 + cc] = v;
                acc[nr][j] = v;
            }
        }
    }
    __syncthreads();
    // ---- z: global panels + gate A panel z-part ----
    if (wn == 0) {
#pragma unroll
        for (int j = 0; j < 4; ++j) {
            int rl = wm * 16 + kseg * 4 + j;
            int row = brow + rl;
#pragma unroll
            for (int nr = 0; nr < 2; ++nr) {
                int cc = nr * 16 + l15;
                float z = acc[nr][j] + eps[(size_t)row * 32 + cc] * Els[rl][cc];
                short zb = f2bf(z);
                inp0[(size_t)row * 224 + cc] = zb;
                inp1[(size_t)row * 288 + cc] = zb;
                inp2[(size_t)row * 288 + cc] = zb;
                int swz = (cc >> 3) ^ ((rl >> 1) & 3);
                gA[rl * 224 + swz * 8 + (cc & 7)] = zb;
            }
        }
    }
    __syncthreads();

    // ---- gate g0: [32,224] @ [224,64] ----
    {
        f32x4 g[2] = {zero4, zero4};
#pragma unroll
        for (int s = 0; s < 7; ++s) {
            bf16x8 av, b[2];
            int rr = wm * 16 + l15;
            int kcp = (s * 4 + kseg) ^ ((rr >> 1) & 3);
            av = *(const bf16x8*)&gA[rr * 224 + kcp * 8];
#pragma unroll
            for (int nr = 0; nr < 2; ++nr) {
                int oo = wn * 32 + nr * 16 + l15;
                int sp = (s * 4 + kseg) ^ ((oo >> 1) & 3);
                b[nr] = *(const bf16x8*)&g0s[oo * 224 + sp * 8];
            }
#pragma unroll
            for (int nr = 0; nr < 2; ++nr)
                g[nr] = __builtin_amdgcn_mfma_f32_16x16x32_bf16(av, b[nr], g[nr], 0, 0, 0);
        }
#pragma unroll
        for (int j = 0; j < 4; ++j) {
            int rl = wm * 16 + kseg * 4 + j;
#pragma unroll
            for (int nr = 0; nr < 2; ++nr) {
                int cc = wn * 32 + nr * 16 + l15;
                float v = elu_f(g[nr][j] + g0b[cc]);
                int swz = (cc >> 3) ^ ((rl >> 1) & 3);
                hA[rl * 64 + swz * 8 + (cc & 7)] = f2bf(v);
            }
        }
    }
    __syncthreads();
    // ---- gate g1: [32,64] @ [64,64] ----
    {
        f32x4 g[2] = {zero4, zero4};
#pragma unroll
        for (int s = 0; s < 2; ++s) {
            bf16x8 av, b[2];
            int rr = wm * 16 + l15;
            int kcp = (s * 4 + kseg) ^ ((rr >> 1) & 3);
            av = *(const bf16x8*)&hA[rr * 64 + kcp * 8];
#pragma unroll
            for (int nr = 0; nr < 2; ++nr) {
                int oo = wn * 32 + nr * 16 + l15;
                int sp = (s * 4 + kseg) ^ ((oo >> 1) & 3);
                b[nr] = *(const bf16x8*)&g1s[oo * 64 + sp * 8];
            }
#pragma unroll
            for (int nr = 0; nr < 2; ++nr)
                g[nr] = __builtin_amdgcn_mfma_f32_16x16x32_bf16(av, b[nr], g[nr], 0, 0, 0);
        }
#pragma unroll
        for (int j = 0; j < 4; ++j) {
            int rl = wm * 16 + kseg * 4 + j;
#pragma unroll
            for (int nr = 0; nr < 2; ++nr) {
                int cc = wn * 32 + nr * 16 + l15;
                float v = elu_f(g[nr][j] + g1b[cc]);
                int swz = (cc >> 3) ^ ((rl >> 1) & 3);
                hB[rl * 64 + swz * 8 + (cc & 7)] = f2bf(v);
            }
        }
    }
    __syncthreads();
    // ---- gate g2 + softmax (waves wn==0 only) ----
    if (wn == 0) {
        f32x4 g = zero4;
#pragma unroll
        for (int s = 0; s < 2; ++s) {
            bf16x8 av, b;
            int rr = wm * 16 + l15;
            int kcp = (s * 4 + kseg) ^ ((rr >> 1) & 3);
            av = *(const bf16x8*)&hB[rr * 64 + kcp * 8];
            int oo = l15;
            int sp = (s * 4 + kseg) ^ ((oo >> 1) & 3);
            b = *(const bf16x8*)&g2s[oo * 64 + sp * 8];
            g = __builtin_amdgcn_mfma_f32_16x16x32_bf16(av, b, g, 0, 0, 0);
        }
        float bv = g2b[l15];
#pragma unroll
        for (int j = 0; j < 4; ++j) {
            int rl = wm * 16 + kseg * 4 + j;
            int row = brow + rl;
            float a2 = g[j] + bv;
            float m = a2;
            for (int off = 1; off < 16; off <<= 1) m = fmaxf(m, __shfl_xor(m, off, 16));
            float ev = expf(a2 - m);
            float sm = ev;
            for (int off = 1; off < 16; off <<= 1) sm += __shfl_xor(sm, off, 16);
            coef[(size_t)row * 16 + l15] = ev / sm;
        }
    }
}

// ---------------------------------------------------------------------------
// moe_gemm: EPG=2 experts/block, 2 K-steps per barrier (8 B-buffers),
// R8-verified core + FUSED finish: last kg-block per (bn,bm) tile reduces
// the 8 partial slices, adds coef@bb, ELU, writes output.
// grid (OP/64, 32, 8).
// ---------------------------------------------------------------------------
template<int KP, int OP, int EPG, int OREAL, bool ACT>
__global__ __launch_bounds__(256, 2) void moe_gemm(
    const short* __restrict__ inp,
    const short* __restrict__ Wt,
    const float* __restrict__ coef,
    const float* __restrict__ bb,
    float* __restrict__ partial,
    short* __restrict__ nxt,
    float* __restrict__ fout,
    int* __restrict__ cnt)
{
    constexpr int NKS = KP / 32;
    constexpr int CHR = KP / 8;
    constexpr int NS = EPG * NKS;          // 14 or 18 (even)

    __shared__ short As[64 * KP];
    __shared__ short Bs[8][64 * 32];
    __shared__ float Cs[64][16];
    __shared__ int lastFlag;

    const int tid = threadIdx.x;
    const int lane = tid & 63;
    const int wid = tid >> 6;
    const int wm = wid >> 1, wn = wid & 1;
    const int bn = blockIdx.x, bm = blockIdx.y, kg = blockIdx.z;
    const int brow = bm * 64, bcol = bn * 64;
    const int wbase = wid * 1024;
    const int kseg = lane >> 4;
    const int l15 = lane & 15;

    // coef first (its compiler-inserted wait stays before our gloads)
    {
        int r = tid >> 2, q = tid & 3;
        float4 v = ((const float4*)(coef + (size_t)(brow + r) * 16))[q];
        *(float4*)&Cs[r][q * 4] = v;
    }
#pragma unroll
    for (int i = 0; i < (64 * KP / 8) / 256; ++i) {
        int ch = i * 256 + tid;
        int r = ch / CHR, kc = ch - r * CHR;
        int kcs = kc ^ ((r >> 1) & 3);
        gload16((char*)As + i * 4096 + wbase,
                inp + (size_t)(brow + r) * KP + kcs * 8);
    }
    auto stageB = [&](int buf, int s) {
        int ei = s / NKS, ks = s - ei * NKS;
        int e = kg * EPG + ei;
        int o = tid >> 2, sl = tid & 3;
        int sp = sl ^ ((o >> 1) & 3);
        gload16((char*)Bs[buf] + wbase,
                Wt + (size_t)(e * OP + bcol + o) * KP + ks * 32 + sp * 8);
    };
    stageB(0, 0); stageB(1, 1); stageB(2, 2);
    stageB(3, 3); stageB(4, 4); stageB(5, 5);
    waitcnt_vm<4>();                        // A + B0,B1 complete (B2..B5 in flight)
    __builtin_amdgcn_s_barrier();

    const f32x4 zero4 = {0.0f, 0.0f, 0.0f, 0.0f};
    f32x4 outacc[2][2] = {{zero4, zero4}, {zero4, zero4}};
    f32x4 acc[2][2];

    auto do_step = [&](int s) {
        int ei = s / NKS, ks = s - ei * NKS;
        if (ks == 0) {
            acc[0][0] = zero4; acc[0][1] = zero4;
            acc[1][0] = zero4; acc[1][1] = zero4;
        }
        bf16x8 a[2], b[2];
#pragma unroll
        for (int mr = 0; mr < 2; ++mr) {
            int rr = wm * 32 + mr * 16 + l15;
            int kcp = (ks * 4 + kseg) ^ ((rr >> 1) & 3);
            a[mr] = *(const bf16x8*)&As[rr * KP + kcp * 8];
        }
#pragma unroll
        for (int nr = 0; nr < 2; ++nr) {
            int oo = wn * 32 + nr * 16 + l15;
            int sp = kseg ^ ((oo >> 1) & 3);
            b[nr] = *(const bf16x8*)&Bs[s & 7][oo * 32 + sp * 8];
        }
#pragma unroll
        for (int mr = 0; mr < 2; ++mr)
#pragma unroll
            for (int nr = 0; nr < 2; ++nr)
                acc[mr][nr] = __builtin_amdgcn_mfma_f32_16x16x32_bf16(
                    a[mr], b[nr], acc[mr][nr], 0, 0, 0);
        if (ks == NKS - 1) {
            int e = kg * EPG + ei;
#pragma unroll
            for (int mr = 0; mr < 2; ++mr) {
                int rb = wm * 32 + mr * 16 + kseg * 4;
#pragma unroll
                for (int j = 0; j < 4; ++j) {
                    float cfv = Cs[rb + j][e];
#pragma unroll
                    for (int nr = 0; nr < 2; ++nr)
                        outacc[mr][nr][j] += cfv * acc[mr][nr][j];
                }
            }
        }
    };

#pragma unroll
    for (int p = 0; p < NS / 2; ++p) {
        int s0 = 2 * p;
        if (s0 + 6 < NS) stageB((s0 + 6) & 7, s0 + 6);
        if (s0 + 7 < NS) stageB((s0 + 7) & 7, s0 + 7);
        do_step(s0);
        do_step(s0 + 1);
        phase_sync(NS - s0 - 2);
    }

    float* pout = partial + (size_t)kg * 2048 * OP;
#pragma unroll
    for (int mr = 0; mr < 2; ++mr)
#pragma unroll
        for (int j = 0; j < 4; ++j) {
            int row = brow + wm * 32 + mr * 16 + kseg * 4 + j;
#pragma unroll
            for (int nr = 0; nr < 2; ++nr) {
                int col = bcol + wn * 32 + nr * 16 + l15;
                pout[(size_t)row * OP + col] = outacc[mr][nr][j];
            }
        }

    // ---- fused finish: last of the 8 kg-blocks per (bn,bm) reduces tile ----
    __threadfence();                 // release our partial writes (device scope)
    __syncthreads();
    if (tid == 0) lastFlag = atomicAdd(&cnt[bm * (OP / 64) + bn], 1);
    __syncthreads();
    if (lastFlag == 7) {
        __threadfence();             // acquire other blocks' partial writes
        float* bbs = (float*)As;     // reuse A LDS (dead after loop)
        for (int i = tid; i < 16 * 64; i += 256) {
            int e = i >> 6, o = i & 63;
            int col = bcol + o;
            bbs[i] = (col < OREAL) ? bb[e * OREAL + col] : 0.0f;
        }
        __syncthreads();
        for (int idx = tid; idx < 64 * 64; idx += 256) {
            int r = idx >> 6, o = idx & 63;
            int row = brow + r, col = bcol + o;
            float v = 0.0f;
#pragma unroll
            for (int g = 0; g < 8; ++g)
                v += partial[(size_t)(g * 2048 + row) * OP + col];
            float bias = 0.0f;
#pragma unroll
            for (int e = 0; e < 16; ++e) bias += Cs[r][e] * bbs[e * 64 + o];
            v += bias;
            if (ACT) v = elu_f(v);
            if (col < OREAL) {
                if (nxt) nxt[(size_t)row * 288 + 32 + col] = f2bf(v);
                else     fout[(size_t)row * OREAL + col] = v;
            }
        }
    }
}

// ---------------------------------------------------------------------------
extern "C" void kernel_launch(void* const* d_in, const int* in_sizes, int n_in,
                              void* d_out, int out_size, void* d_ws, size_t ws_size,
                              hipStream_t stream)
{
    const float* x    = (const float*)d_in[0];
    const float* c    = (const float*)d_in[1];
    const float* eps  = (const float*)d_in[2];
    const float* fc1w = (const float*)d_in[3];
    const float* fc1b = (const float*)d_in[4];
    const float* fc2w = (const float*)d_in[5];
    const float* fc2b = (const float*)d_in[6];
    const float* muw  = (const float*)d_in[7];
    const float* mub  = (const float*)d_in[8];
    const float* lvw  = (const float*)d_in[9];
    const float* lvb  = (const float*)d_in[10];
    const float* g0w  = (const float*)d_in[11];
    const float* g0b  = (const float*)d_in[12];
    const float* g1w  = (const float*)d_in[13];
    const float* g1b  = (const float*)d_in[14];
    const float* g2w  = (const float*)d_in[15];
    const float* g2b  = (const float*)d_in[16];
    const float* w0   = (const float*)d_in[17];
    const float* b0   = (const float*)d_in[18];
    const float* w1   = (const float*)d_in[19];
    const float* b1   = (const float*)d_in[20];
    const float* w2   = (const float*)d_in[21];
    const float* b2   = (const float*)d_in[22];

    float* out       = (float*)d_out;
    float* out_layer = out;                       // [2048,171]
    float* out_mu    = out + NB * NOUT;           // [2048,32]
    float* out_lv    = out_mu + NB * NL;          // [2048,32]

    float* ws      = (float*)d_ws;
    float* partial = ws;                          // 8*2048*256 f32 = 16 MB
    float* cf      = partial + 8 * 2048 * 256;    // 2048*16 f32
    short* xc    = (short*)(cf + 32768);          // 2048*384
    short* xh1   = xc   + (size_t)2048 * 384;     // 2048*448
    short* xh2   = xh1  + (size_t)2048 * 448;     // 2048*448
    short* inp0  = xh2  + (size_t)2048 * 448;     // 2048*224
    short* inp1  = inp0 + (size_t)2048 * 224;     // 2048*288
    short* inp2  = inp1 + (size_t)2048 * 288;     // 2048*288
    short* fc1Wt = inp2 + (size_t)2048 * 288;     // 256*384
    short* fc2Wt = fc1Wt + 256 * 384;             // 256*448
    short* mlWt  = fc2Wt + 256 * 448;             // 64*448
    short* Wt0   = mlWt + 64 * 448;               // 16*256*224
    short* Wt1   = Wt0 + 16 * 256 * 224;          // 16*256*288
    short* Wt2   = Wt1 + 16 * 256 * 288;          // 16*192*288
    short* g0wt  = Wt2 + 16 * 192 * 288;          // 64*224
    short* g1wt  = g0wt + 64 * 224;               // 64*64
    short* g2wt  = g1wt + 64 * 64;                // 32*64
    int*   cnts  = (int*)(g2wt + 32 * 64);        // 384 ints (3 x 128)

    dim3 blk(256);

    // preprocessing: all weight transposes + input panels + counter zeroing
    prep_all<<<dim3(3168 + 2048), blk, 0, stream>>>(
        fc1w, fc2w, muw, lvw, w0, w1, w2, g0w, g1w, g2w,
        fc1Wt, fc2Wt, mlWt, mlWt + 32 * 448, Wt0, Wt1, Wt2, g0wt, g1wt, g2wt,
        x, c, xc, xh1, xh2, inp0, cnts);

    // encoder chain (bf16 MFMA, BM=32/BK=64 pipelined)
    enc_gemm<384><<<dim3(4, 64), blk, 0, stream>>>(xc,  fc1Wt, fc1b, xh1, 448, 171);
    enc_gemm<448><<<dim3(4, 64), blk, 0, stream>>>(xh1, fc2Wt, fc2b, xh2, 448, 171);
    // mu/lv/z + fused gate
    mulvz_gate<<<dim3(1, 64), blk, 0, stream>>>(
        xh2, mlWt, mub, lvb, eps, g0wt, g1wt, g2wt, g0b, g1b, g2b,
        out_mu, out_lv, inp0, inp1, inp2, cf);

    // MoE layers with fused finish: EPG=2 -> 8 expert-groups, 1024/768 blocks
    moe_gemm<224, 256, 2, 256, true><<<dim3(4, 32, 8), blk, 0, stream>>>(
        inp0, Wt0, cf, b0, partial, inp1, nullptr, cnts);
    moe_gemm<288, 256, 2, 256, true><<<dim3(4, 32, 8), blk, 0, stream>>>(
        inp1, Wt1, cf, b1, partial, inp2, nullptr, cnts + 128);
    moe_gemm<288, 192, 2, 171, false><<<dim3(3, 32, 8), blk, 0, stream>>>(
        inp2, Wt2, cf, b2, partial, nullptr, out_layer, cnts + 256);
}

// Round 12
// 99.855 us; speedup vs baseline: 4.3135x; 4.3135x over previous
//
#include <hip/hip_runtime.h>
#include <math.h>

// Problem constants
#define NB   2048
#define NFC  171
#define NFR  171
#define NL   32
#define NH   256
#define NE   16
#define NGH  64
#define NIN  203   /* L + FC */
#define NINT 288   /* L + H  */
#define NOUT 171

typedef __attribute__((ext_vector_type(8))) short bf16x8;   // 8 bf16 in 4 VGPRs
typedef __attribute__((ext_vector_type(4))) float f32x4;    // MFMA acc

__device__ __forceinline__ float elu_f(float v) {
    return v > 0.0f ? v : expm1f(v);
}

// f32 -> bf16 bits, round-to-nearest-even
__device__ __forceinline__ short f2bf(float f) {
    unsigned u = __float_as_uint(f);
    unsigned r = (u + 0x7FFFu + ((u >> 16) & 1u)) >> 16;
    return (short)r;
}

// async global->LDS, 16 bytes per lane; lds base must be wave-uniform
__device__ __forceinline__ void gload16(void* lds, const void* g) {
    __builtin_amdgcn_global_load_lds(
        (const __attribute__((address_space(1))) unsigned*)g,
        (__attribute__((address_space(3))) unsigned*)lds, 16, 0, 0);
}

template<int N> __device__ __forceinline__ void waitcnt_vm() {
    if constexpr (N == 0)      asm volatile("s_waitcnt vmcnt(0) lgkmcnt(0)" ::: "memory");
    else if constexpr (N == 1) asm volatile("s_waitcnt vmcnt(1) lgkmcnt(0)" ::: "memory");
    else if constexpr (N == 2) asm volatile("s_waitcnt vmcnt(2) lgkmcnt(0)" ::: "memory");
    else if constexpr (N == 3) asm volatile("s_waitcnt vmcnt(3) lgkmcnt(0)" ::: "memory");
    else                       asm volatile("s_waitcnt vmcnt(4) lgkmcnt(0)" ::: "memory");
}
// BK=64 path (enc/mulvz): 2 loads per B-stage, 4 buffers
__device__ __forceinline__ void loop_sync64(int s, int NS) {
    if (s + 3 < NS)      waitcnt_vm<4>();
    else if (s + 2 < NS) waitcnt_vm<2>();
    else                 waitcnt_vm<0>();
    __builtin_amdgcn_s_barrier();
}
// MoE 2-step phase: rem = steps not yet consumed after this phase
__device__ __forceinline__ void phase_sync(int rem) {
    if (rem >= 6)      waitcnt_vm<4>();
    else if (rem == 5) waitcnt_vm<3>();
    else if (rem == 4) waitcnt_vm<2>();
    else if (rem == 3) waitcnt_vm<1>();
    else               waitcnt_vm<0>();
    __builtin_amdgcn_s_barrier();
}

// ---------------------------------------------------------------------------
// prep_all: blocks [0,3168) = weight transpose tiles; [3168, 3168+2048) = panels
// ---------------------------------------------------------------------------
__global__ __launch_bounds__(256) void prep_all(
    const float* s0, const float* s1, const float* s2, const float* s3,
    const float* s4, const float* s5, const float* s6,
    const float* s7, const float* s8, const float* s9,
    short* d0, short* d1, short* d2, short* d3,
    short* d4, short* d5, short* d6, short* d7, short* d8, short* d9,
    const float* __restrict__ x, const float* __restrict__ c,
    short* __restrict__ xc, short* __restrict__ xh1, short* __restrict__ xh2,
    short* __restrict__ inp0)
{
    __shared__ float T[32][33];
    const int tid = threadIdx.x;

    if (blockIdx.x >= 3168) {
        // ---- input panels, one block per batch row ----
        const int b = blockIdx.x - 3168;
        for (int i = tid; i < 384; i += 256) {
            float v = (i < 171) ? x[b * 171 + i] : ((i < 342) ? c[b * 171 + (i - 171)] : 0.0f);
            xc[(size_t)b * 384 + i] = f2bf(v);
        }
        for (int i = tid; i < 171; i += 256) {
            short v = f2bf(x[b * 171 + i]);
            xh1[(size_t)b * 448 + i] = v;
            xh2[(size_t)b * 448 + i] = v;
        }
        for (int i = tid; i < 21; i += 256) {
            xh1[(size_t)b * 448 + 427 + i] = 0;
            xh2[(size_t)b * 448 + 427 + i] = 0;
        }
        for (int i = tid; i < 192; i += 256) {
            inp0[(size_t)b * 224 + 32 + i] = (i < 171) ? f2bf(c[b * 171 + i]) : (short)0;
        }
        return;
    }

    // ---- weight transpose tiles (10 segments) ----
    constexpr int K_[10]   = {342, 427, 427, 427, 203, 288, 288, 203,  64,  64};
    constexpr int O_[10]   = {256, 256,  32,  32, 256, 256, 171,  64,  64,  16};
    constexpr int KP_[10]  = {384, 448, 448, 448, 224, 288, 288, 224,  64,  64};
    constexpr int OP_[10]  = {256, 256,  64,  64, 256, 256, 192,  64,  64,  32};
    constexpr int nKT_[10] = { 12,  14,  14,  14,   7,   9,   9,   7,   2,   2};
    constexpr int tpe_[10] = { 96, 112,  14,  14,  56,  72,  54,  14,   4,   2};
    constexpr int st_[10]  = {  0,  96, 208, 222, 236,1132,2284,3148,3162,3166};
    const float* srcs[10] = {s0, s1, s2, s3, s4, s5, s6, s7, s8, s9};
    short*       dsts[10] = {d0, d1, d2, d3, d4, d5, d6, d7, d8, d9};

    int t = blockIdx.x;
    int s = 0;
    while (s < 9 && t >= st_[s + 1]) ++s;
    int local = t - st_[s];
    int e = local / tpe_[s];
    int rem = local - e * tpe_[s];
    int ox = rem / nKT_[s];
    int ky = rem - ox * nKT_[s];
    const int K = K_[s], O = O_[s], KP = KP_[s], OP = OP_[s];
    const float* src = srcs[s];
    short* dst = dsts[s];

    const int cc = tid & 31, r0 = tid >> 5;
#pragma unroll
    for (int i = 0; i < 4; ++i) {
        int r = r0 + i * 8;
        int gk = ky * 32 + r, go = ox * 32 + cc;
        T[r][cc] = (gk < K && go < O) ? src[((size_t)e * K + gk) * O + go] : 0.0f;
    }
    __syncthreads();
#pragma unroll
    for (int i = 0; i < 4; ++i) {
        int r = r0 + i * 8;
        int go = ox * 32 + r, gk = ky * 32 + cc;
        dst[((size_t)e * OP + go) * KP + gk] = f2bf(T[cc][r]);
    }
}

// ---------------------------------------------------------------------------
// enc_gemm: BM=32, BN=64, BK=64.  grid (NO/64, 64)   (verified R5)
// ---------------------------------------------------------------------------
template<int KP>
__global__ __launch_bounds__(256, 2) void enc_gemm(
    const short* __restrict__ A,
    const short* __restrict__ Wt,
    const float* __restrict__ bias,
    short* __restrict__ dst, int dstld, int dstoff)
{
    constexpr int NKS = KP / 64;
    constexpr int CHR = KP / 8;

    __shared__ short As[32 * KP];
    __shared__ short Bs[4][64 * 64];

    const int tid = threadIdx.x;
    const int lane = tid & 63;
    const int wid = tid >> 6;
    const int wm = wid & 1, wn = wid >> 1;
    const int brow = blockIdx.y * 32, bcol = blockIdx.x * 64;
    const int wbase = wid * 1024;
    const int kseg = lane >> 4;

#pragma unroll
    for (int i = 0; i < (32 * CHR) / 256; ++i) {
        int ch = i * 256 + tid;
        int r = ch / CHR, kc = ch - r * CHR;
        int kcs = kc ^ ((r >> 1) & 3);
        gload16((char*)As + i * 4096 + wbase, A + (size_t)(brow + r) * KP + kcs * 8);
    }
    auto stageB = [&](int buf, int ks) {
#pragma unroll
        for (int g = 0; g < 2; ++g) {
            int ch = g * 256 + tid;
            int o = ch >> 3, sl = ch & 7;
            int sp = sl ^ ((o >> 1) & 3);
            gload16((char*)Bs[buf] + g * 4096 + wbase,
                    Wt + (size_t)(bcol + o) * KP + ks * 64 + sp * 8);
        }
    };
    stageB(0, 0); stageB(1, 1); stageB(2, 2);
    waitcnt_vm<4>();
    __builtin_amdgcn_s_barrier();

    const f32x4 zero4 = {0.0f, 0.0f, 0.0f, 0.0f};
    f32x4 acc[2] = {zero4, zero4};

    for (int s = 0; s < NKS; ++s) {
        if (s + 3 < NKS) stageB((s + 3) & 3, s + 3);
#pragma unroll
        for (int kk = 0; kk < 2; ++kk) {
            bf16x8 a, b[2];
            int rr = wm * 16 + (lane & 15);
            int kcp = (s * 8 + kk * 4 + kseg) ^ ((rr >> 1) & 3);
            a = *(const bf16x8*)&As[rr * KP + kcp * 8];
#pragma unroll
            for (int nr = 0; nr < 2; ++nr) {
                int oo = wn * 32 + nr * 16 + (lane & 15);
                int sp = (kk * 4 + kseg) ^ ((oo >> 1) & 3);
                b[nr] = *(const bf16x8*)&Bs[s & 3][oo * 64 + sp * 8];
            }
#pragma unroll
            for (int nr = 0; nr < 2; ++nr)
                acc[nr] = __builtin_amdgcn_mfma_f32_16x16x32_bf16(a, b[nr], acc[nr], 0, 0, 0);
        }
        loop_sync64(s, NKS);
    }

#pragma unroll
    for (int j = 0; j < 4; ++j) {
        int row = brow + wm * 16 + kseg * 4 + j;
#pragma unroll
        for (int nr = 0; nr < 2; ++nr) {
            int col = bcol + wn * 32 + nr * 16 + (lane & 15);
            float v = acc[nr][j] + bias[col];
            dst[(size_t)row * dstld + dstoff + col] = f2bf(elu_f(v));
        }
    }
}

// ---------------------------------------------------------------------------
// mulvz_gate: BM=32, grid (1,64).  (verified R5)
// ---------------------------------------------------------------------------
__global__ __launch_bounds__(256) void mulvz_gate(
    const short* __restrict__ A,             // xh2 [2048][448]
    const short* __restrict__ Wt,            // mlWt [64][448]
    const float* __restrict__ mub, const float* __restrict__ lvb,
    const float* __restrict__ eps,
    const short* __restrict__ g0wt,          // [64][224]
    const short* __restrict__ g1wt,          // [64][64]
    const short* __restrict__ g2wt,          // [32][64] rows 16..31 zero
    const float* __restrict__ g0b, const float* __restrict__ g1b,
    const float* __restrict__ g2b,
    float* __restrict__ mu_out, float* __restrict__ lv_out,
    short* __restrict__ inp0, short* __restrict__ inp1, short* __restrict__ inp2,
    float* __restrict__ coef)
{
    constexpr int KP = 448;
    constexpr int NKS = KP / 64;   // 7
    constexpr int CHR = KP / 8;    // 56

    __shared__ short As[32 * 448];
    __shared__ short Bs[4][64 * 64];
    __shared__ float Els[32][32];
    __shared__ short gA[32 * 224];
    __shared__ short g0s[64 * 224];
    __shared__ short g1s[64 * 64];
    __shared__ short g2s[32 * 64];
    __shared__ short hA[32 * 64];
    __shared__ short hB[32 * 64];

    const int tid = threadIdx.x;
    const int lane = tid & 63;
    const int wid = tid >> 6;
    const int wm = wid & 1, wn = wid >> 1;
    const int brow = blockIdx.y * 32;
    const int wbase = wid * 1024;
    const int kseg = lane >> 4;
    const int l15 = lane & 15;

    // ---- A panel (7 gloads) ----
#pragma unroll
    for (int i = 0; i < 7; ++i) {
        int ch = i * 256 + tid;
        int r = ch / CHR, kc = ch - r * CHR;
        int kcs = kc ^ ((r >> 1) & 3);
        gload16((char*)As + i * 4096 + wbase, A + (size_t)(brow + r) * KP + kcs * 8);
    }
    // ---- gate A panel c-part from inp0 ----
#pragma unroll
    for (int i = 0; i < 4; ++i) {
        int ch = i * 256 + tid;
        if (ch < 896) {
            int r = ch / 28, kc = ch - r * 28;
            int kcs = kc ^ ((r >> 1) & 3);
            gload16((char*)gA + i * 4096 + wbase, inp0 + (size_t)(brow + r) * 224 + kcs * 8);
        }
    }
    // ---- gate weights ----
#pragma unroll
    for (int i = 0; i < 7; ++i) {
        int ch = i * 256 + tid;
        int r = ch / 28, kc = ch - r * 28;
        int kcs = kc ^ ((r >> 1) & 3);
        gload16((char*)g0s + i * 4096 + wbase, g0wt + (size_t)r * 224 + kcs * 8);
    }
#pragma unroll
    for (int i = 0; i < 2; ++i) {
        int ch = i * 256 + tid;
        int r = ch >> 3, kc = ch & 7;
        int kcs = kc ^ ((r >> 1) & 3);
        gload16((char*)g1s + i * 4096 + wbase, g1wt + (size_t)r * 64 + kcs * 8);
    }
    {
        int ch = tid;
        int r = ch >> 3, kc = ch & 7;
        int kcs = kc ^ ((r >> 1) & 3);
        gload16((char*)g2s + wbase, g2wt + (size_t)r * 64 + kcs * 8);
    }
    // ---- B double-buffer ----
    auto stageB = [&](int buf, int ks) {
#pragma unroll
        for (int g = 0; g < 2; ++g) {
            int ch = g * 256 + tid;
            int o = ch >> 3, sl = ch & 7;
            int sp = sl ^ ((o >> 1) & 3);
            gload16((char*)Bs[buf] + g * 4096 + wbase,
                    Wt + (size_t)o * KP + ks * 64 + sp * 8);
        }
    };
    stageB(0, 0); stageB(1, 1); stageB(2, 2);
    waitcnt_vm<4>();
    __builtin_amdgcn_s_barrier();

    const f32x4 zero4 = {0.0f, 0.0f, 0.0f, 0.0f};
    f32x4 acc[2] = {zero4, zero4};

    for (int s = 0; s < NKS; ++s) {
        if (s + 3 < NKS) stageB((s + 3) & 3, s + 3);
#pragma unroll
        for (int kk = 0; kk < 2; ++kk) {
            bf16x8 av, b[2];
            int rr = wm * 16 + l15;
            int kcp = (s * 8 + kk * 4 + kseg) ^ ((rr >> 1) & 3);
            av = *(const bf16x8*)&As[rr * KP + kcp * 8];
#pragma unroll
            for (int nr = 0; nr < 2; ++nr) {
                int oo = wn * 32 + nr * 16 + l15;
                int sp = (kk * 4 + kseg) ^ ((oo >> 1) & 3);
                b[nr] = *(const bf16x8*)&Bs[s & 3][oo * 64 + sp * 8];
            }
#pragma unroll
            for (int nr = 0; nr < 2; ++nr)
                acc[nr] = __builtin_amdgcn_mfma_f32_16x16x32_bf16(av, b[nr], acc[nr], 0, 0, 0);
        }
        loop_sync64(s, NKS);
    }

    // ---- mu / lv epilogue ----
#pragma unroll
    for (int j = 0; j < 4; ++j) {
        int rl = wm * 16 + kseg * 4 + j;
        int row = brow + rl;
#pragma unroll
        for (int nr = 0; nr < 2; ++nr) {
            int cc = nr * 16 + l15;              // 0..31
            if (wn == 1) {
                float v = acc[nr][j] + lvb[cc];
                lv_out[(size_t)row * 32 + cc] = v;
                Els[rl][cc] = expf(0.5f * v);
            } else {
                float v = acc[nr][j] + mub[cc];
                mu_out[(size_t)row * 32 + cc] = v;
                acc[nr][j] = v;
            }
        }
    }
    __syncthreads();
    // ---- z: global panels + gate A panel z-part ----
    if (wn == 0) {
#pragma unroll
        for (int j = 0; j < 4; ++j) {
            int rl = wm * 16 + kseg * 4 + j;
            int row = brow + rl;
#pragma unroll
            for (int nr = 0; nr < 2; ++nr) {
                int cc = nr * 16 + l15;
                float z = acc[nr][j] + eps[(size_t)row * 32 + cc] * Els[rl][cc];
                short zb = f2bf(z);
                inp0[(size_t)row * 224 + cc] = zb;
                inp1[(size_t)row * 288 + cc] = zb;
                inp2[(size_t)row * 288 + cc] = zb;
                int swz = (cc >> 3) ^ ((rl >> 1) & 3);
                gA[rl * 224 + swz * 8 + (cc & 7)] = zb;
            }
        }
    }
    __syncthreads();

    // ---- gate g0: [32,224] @ [224,64] ----
    {
        f32x4 g[2] = {zero4, zero4};
#pragma unroll
        for (int s = 0; s < 7; ++s) {
            bf16x8 av, b[2];
            int rr = wm * 16 + l15;
            int kcp = (s * 4 + kseg) ^ ((rr >> 1) & 3);
            av = *(const bf16x8*)&gA[rr * 224 + kcp * 8];
#pragma unroll
            for (int nr = 0; nr < 2; ++nr) {
                int oo = wn * 32 + nr * 16 + l15;
                int sp = (s * 4 + kseg) ^ ((oo >> 1) & 3);
                b[nr] = *(const bf16x8*)&g0s[oo * 224 + sp * 8];
            }
#pragma unroll
            for (int nr = 0; nr < 2; ++nr)
                g[nr] = __builtin_amdgcn_mfma_f32_16x16x32_bf16(av, b[nr], g[nr], 0, 0, 0);
        }
#pragma unroll
        for (int j = 0; j < 4; ++j) {
            int rl = wm * 16 + kseg * 4 + j;
#pragma unroll
            for (int nr = 0; nr < 2; ++nr) {
                int cc = wn * 32 + nr * 16 + l15;
                float v = elu_f(g[nr][j] + g0b[cc]);
                int swz = (cc >> 3) ^ ((rl >> 1) & 3);
                hA[rl * 64 + swz * 8 + (cc & 7)] = f2bf(v);
            }
        }
    }
    __syncthreads();
    // ---- gate g1: [32,64] @ [64,64] ----
    {
        f32x4 g[2] = {zero4, zero4};
#pragma unroll
        for (int s = 0; s < 2; ++s) {
            bf16x8 av, b[2];
            int rr = wm * 16 + l15;
            int kcp = (s * 4 + kseg) ^ ((rr >> 1) & 3);
            av = *(const bf16x8*)&hA[rr * 64 + kcp * 8];
#pragma unroll
            for (int nr = 0; nr < 2; ++nr) {
                int oo = wn * 32 + nr * 16 + l15;
                int sp = (s * 4 + kseg) ^ ((oo >> 1) & 3);
                b[nr] = *(const bf16x8*)&g1s[oo * 64 + sp * 8];
            }
#pragma unroll
            for (int nr = 0; nr < 2; ++nr)
                g[nr] = __builtin_amdgcn_mfma_f32_16x16x32_bf16(av, b[nr], g[nr], 0, 0, 0);
        }
#pragma unroll
        for (int j = 0; j < 4; ++j) {
            int rl = wm * 16 + kseg * 4 + j;
#pragma unroll
            for (int nr = 0; nr < 2; ++nr) {
                int cc = wn * 32 + nr * 16 + l15;
                float v = elu_f(g[nr][j] + g1b[cc]);
                int swz = (cc >> 3) ^ ((rl >> 1) & 3);
                hB[rl * 64 + swz * 8 + (cc & 7)] = f2bf(v);
            }
        }
    }
    __syncthreads();
    // ---- gate g2 + softmax (waves wn==0 only) ----
    if (wn == 0) {
        f32x4 g = zero4;
#pragma unroll
        for (int s = 0; s < 2; ++s) {
            bf16x8 av, b;
            int rr = wm * 16 + l15;
            int kcp = (s * 4 + kseg) ^ ((rr >> 1) & 3);
            av = *(const bf16x8*)&hB[rr * 64 + kcp * 8];
            int oo = l15;
            int sp = (s * 4 + kseg) ^ ((oo >> 1) & 3);
            b = *(const bf16x8*)&g2s[oo * 64 + sp * 8];
            g = __builtin_amdgcn_mfma_f32_16x16x32_bf16(av, b, g, 0, 0, 0);
        }
        float bv = g2b[l15];
#pragma unroll
        for (int j = 0; j < 4; ++j) {
            int rl = wm * 16 + kseg * 4 + j;
            int row = brow + rl;
            float a2 = g[j] + bv;
            float m = a2;
            for (int off = 1; off < 16; off <<= 1) m = fmaxf(m, __shfl_xor(m, off, 16));
            float ev = expf(a2 - m);
            float sm = ev;
            for (int off = 1; off < 16; off <<= 1) sm += __shfl_xor(sm, off, 16);
            coef[(size_t)row * 16 + l15] = ev / sm;
        }
    }
}

// ---------------------------------------------------------------------------
// moe_gemm: EPG=2 experts/block, 2 K-steps per barrier (8 B-buffers).
// grid (OP/64, 32, 8).   (R8-verified, best measured)
// ---------------------------------------------------------------------------
template<int KP, int OP, int EPG>
__global__ __launch_bounds__(256, 2) void moe_gemm(
    const short* __restrict__ inp,
    const short* __restrict__ Wt,
    const float* __restrict__ coef,
    float* __restrict__ partial)
{
    constexpr int NKS = KP / 32;
    constexpr int CHR = KP / 8;
    constexpr int NS = EPG * NKS;          // 14 or 18 (even)

    __shared__ short As[64 * KP];
    __shared__ short Bs[8][64 * 32];
    __shared__ float Cs[64][16];

    const int tid = threadIdx.x;
    const int lane = tid & 63;
    const int wid = tid >> 6;
    const int wm = wid >> 1, wn = wid & 1;
    const int bn = blockIdx.x, bm = blockIdx.y, kg = blockIdx.z;
    const int brow = bm * 64, bcol = bn * 64;
    const int wbase = wid * 1024;
    const int kseg = lane >> 4;
    const int l15 = lane & 15;

    // coef first (its compiler-inserted wait stays before our gloads)
    {
        int r = tid >> 2, q = tid & 3;
        float4 v = ((const float4*)(coef + (size_t)(brow + r) * 16))[q];
        *(float4*)&Cs[r][q * 4] = v;
    }
#pragma unroll
    for (int i = 0; i < (64 * KP / 8) / 256; ++i) {
        int ch = i * 256 + tid;
        int r = ch / CHR, kc = ch - r * CHR;
        int kcs = kc ^ ((r >> 1) & 3);
        gload16((char*)As + i * 4096 + wbase,
                inp + (size_t)(brow + r) * KP + kcs * 8);
    }
    auto stageB = [&](int buf, int s) {
        int ei = s / NKS, ks = s - ei * NKS;
        int e = kg * EPG + ei;
        int o = tid >> 2, sl = tid & 3;
        int sp = sl ^ ((o >> 1) & 3);
        gload16((char*)Bs[buf] + wbase,
                Wt + (size_t)(e * OP + bcol + o) * KP + ks * 32 + sp * 8);
    };
    stageB(0, 0); stageB(1, 1); stageB(2, 2);
    stageB(3, 3); stageB(4, 4); stageB(5, 5);
    waitcnt_vm<4>();                        // A + B0,B1 complete (B2..B5 in flight)
    __builtin_amdgcn_s_barrier();

    const f32x4 zero4 = {0.0f, 0.0f, 0.0f, 0.0f};
    f32x4 outacc[2][2] = {{zero4, zero4}, {zero4, zero4}};
    f32x4 acc[2][2];

    auto do_step = [&](int s) {
        int ei = s / NKS, ks = s - ei * NKS;
        if (ks == 0) {
            acc[0][0] = zero4; acc[0][1] = zero4;
            acc[1][0] = zero4; acc[1][1] = zero4;
        }
        bf16x8 a[2], b[2];
#pragma unroll
        for (int mr = 0; mr < 2; ++mr) {
            int rr = wm * 32 + mr * 16 + l15;
            int kcp = (ks * 4 + kseg) ^ ((rr >> 1) & 3);
            a[mr] = *(const bf16x8*)&As[rr * KP + kcp * 8];
        }
#pragma unroll
        for (int nr = 0; nr < 2; ++nr) {
            int oo = wn * 32 + nr * 16 + l15;
            int sp = kseg ^ ((oo >> 1) & 3);
            b[nr] = *(const bf16x8*)&Bs[s & 7][oo * 32 + sp * 8];
        }
#pragma unroll
        for (int mr = 0; mr < 2; ++mr)
#pragma unroll
            for (int nr = 0; nr < 2; ++nr)
                acc[mr][nr] = __builtin_amdgcn_mfma_f32_16x16x32_bf16(
                    a[mr], b[nr], acc[mr][nr], 0, 0, 0);
        if (ks == NKS - 1) {
            int e = kg * EPG + ei;
#pragma unroll
            for (int mr = 0; mr < 2; ++mr) {
                int rb = wm * 32 + mr * 16 + kseg * 4;
#pragma unroll
                for (int j = 0; j < 4; ++j) {
                    float cfv = Cs[rb + j][e];
#pragma unroll
                    for (int nr = 0; nr < 2; ++nr)
                        outacc[mr][nr][j] += cfv * acc[mr][nr][j];
                }
            }
        }
    };

    for (int p = 0; p < NS / 2; ++p) {
        int s0 = 2 * p;
        if (s0 + 6 < NS) stageB((s0 + 6) & 7, s0 + 6);
        if (s0 + 7 < NS) stageB((s0 + 7) & 7, s0 + 7);
        do_step(s0);
        do_step(s0 + 1);
        phase_sync(NS - s0 - 2);
    }

    float* pout = partial + (size_t)kg * 2048 * OP;
#pragma unroll
    for (int mr = 0; mr < 2; ++mr)
#pragma unroll
        for (int j = 0; j < 4; ++j) {
            int row = brow + wm * 32 + mr * 16 + kseg * 4 + j;
#pragma unroll
            for (int nr = 0; nr < 2; ++nr) {
                int col = bcol + wn * 32 + nr * 16 + l15;
                pout[(size_t)row * OP + col] = outacc[mr][nr][j];
            }
        }
}

// ---------------------------------------------------------------------------
// moe_finish: sum NKG partial slices (float4) + coef@bb; act; write.
// ---------------------------------------------------------------------------
template<int NP, int O, bool ACT, int NKG>
__global__ __launch_bounds__(256) void moe_finish(
    const float* __restrict__ partial,
    const float* __restrict__ coef,
    const float* __restrict__ bb,
    short* __restrict__ nxt,
    float* __restrict__ fout)
{
    __shared__ float bbs[16 * O];
    __shared__ float cfs[8][16];
    const int tid = threadIdx.x;
    const int row0 = blockIdx.x * 8;

    for (int i = tid; i < 16 * O; i += 256) bbs[i] = bb[i];
    if (tid < 128) cfs[tid >> 4][tid & 15] = coef[(row0 + (tid >> 4)) * 16 + (tid & 15)];
    __syncthreads();

    constexpr int NG = NP / 4;
    for (int idx = tid; idx < 8 * NG; idx += 256) {
        int r = idx / NG, og = idx - r * NG;
        int o = og * 4;
        int row = row0 + r;
        float4 v = {0.f, 0.f, 0.f, 0.f};
#pragma unroll
        for (int kg = 0; kg < NKG; ++kg) {
            float4 p = *(const float4*)&partial[(size_t)(kg * 2048 + row) * NP + o];
            v.x += p.x; v.y += p.y; v.z += p.z; v.w += p.w;
        }
        float vv[4] = {v.x, v.y, v.z, v.w};
#pragma unroll
        for (int t = 0; t < 4; ++t) {
            int oo = o + t;
            if (oo < O) {
                float bias = 0.0f;
#pragma unroll
                for (int e = 0; e < 16; ++e) bias += cfs[r][e] * bbs[e * O + oo];
                float val = vv[t] + bias;
                if (ACT) val = elu_f(val);
                if (nxt) nxt[(size_t)row * 288 + 32 + oo] = f2bf(val);
                else     fout[(size_t)row * O + oo] = val;
            }
        }
    }
}

// ---------------------------------------------------------------------------
extern "C" void kernel_launch(void* const* d_in, const int* in_sizes, int n_in,
                              void* d_out, int out_size, void* d_ws, size_t ws_size,
                              hipStream_t stream)
{
    const float* x    = (const float*)d_in[0];
    const float* c    = (const float*)d_in[1];
    const float* eps  = (const float*)d_in[2];
    const float* fc1w = (const float*)d_in[3];
    const float* fc1b = (const float*)d_in[4];
    const float* fc2w = (const float*)d_in[5];
    const float* fc2b = (const float*)d_in[6];
    const float* muw  = (const float*)d_in[7];
    const float* mub  = (const float*)d_in[8];
    const float* lvw  = (const float*)d_in[9];
    const float* lvb  = (const float*)d_in[10];
    const float* g0w  = (const float*)d_in[11];
    const float* g0b  = (const float*)d_in[12];
    const float* g1w  = (const float*)d_in[13];
    const float* g1b  = (const float*)d_in[14];
    const float* g2w  = (const float*)d_in[15];
    const float* g2b  = (const float*)d_in[16];
    const float* w0   = (const float*)d_in[17];
    const float* b0   = (const float*)d_in[18];
    const float* w1   = (const float*)d_in[19];
    const float* b1   = (const float*)d_in[20];
    const float* w2   = (const float*)d_in[21];
    const float* b2   = (const float*)d_in[22];

    float* out       = (float*)d_out;
    float* out_layer = out;                       // [2048,171]
    float* out_mu    = out + NB * NOUT;           // [2048,32]
    float* out_lv    = out_mu + NB * NL;          // [2048,32]

    float* ws      = (float*)d_ws;
    float* partial = ws;                          // 8*2048*256 f32 = 16 MB
    float* cf      = partial + 8 * 2048 * 256;    // 2048*16 f32
    short* xc    = (short*)(cf + 32768);          // 2048*384
    short* xh1   = xc   + (size_t)2048 * 384;     // 2048*448
    short* xh2   = xh1  + (size_t)2048 * 448;     // 2048*448
    short* inp0  = xh2  + (size_t)2048 * 448;     // 2048*224
    short* inp1  = inp0 + (size_t)2048 * 224;     // 2048*288
    short* inp2  = inp1 + (size_t)2048 * 288;     // 2048*288
    short* fc1Wt = inp2 + (size_t)2048 * 288;     // 256*384
    short* fc2Wt = fc1Wt + 256 * 384;             // 256*448
    short* mlWt  = fc2Wt + 256 * 448;             // 64*448
    short* Wt0   = mlWt + 64 * 448;               // 16*256*224
    short* Wt1   = Wt0 + 16 * 256 * 224;          // 16*256*288
    short* Wt2   = Wt1 + 16 * 256 * 288;          // 16*192*288
    short* g0wt  = Wt2 + 16 * 192 * 288;          // 64*224
    short* g1wt  = g0wt + 64 * 224;               // 64*64
    short* g2wt  = g1wt + 64 * 64;                // 32*64

    dim3 blk(256);

    // preprocessing: all weight transposes + input panels in one launch
    prep_all<<<dim3(3168 + 2048), blk, 0, stream>>>(
        fc1w, fc2w, muw, lvw, w0, w1, w2, g0w, g1w, g2w,
        fc1Wt, fc2Wt, mlWt, mlWt + 32 * 448, Wt0, Wt1, Wt2, g0wt, g1wt, g2wt,
        x, c, xc, xh1, xh2, inp0);

    // encoder chain (bf16 MFMA, BM=32/BK=64 pipelined)
    enc_gemm<384><<<dim3(4, 64), blk, 0, stream>>>(xc,  fc1Wt, fc1b, xh1, 448, 171);
    enc_gemm<448><<<dim3(4, 64), blk, 0, stream>>>(xh1, fc2Wt, fc2b, xh2, 448, 171);
    // mu/lv/z + fused gate
    mulvz_gate<<<dim3(1, 64), blk, 0, stream>>>(
        xh2, mlWt, mub, lvb, eps, g0wt, g1wt, g2wt, g0b, g1b, g2b,
        out_mu, out_lv, inp0, inp1, inp2, cf);

    // MoE layers: EPG=2 -> 8 expert-groups, 1024/768 blocks
    moe_gemm<224, 256, 2><<<dim3(4, 32, 8), blk, 0, stream>>>(inp0, Wt0, cf, partial);
    moe_finish<256, 256, true, 8><<<dim3(256), blk, 0, stream>>>(partial, cf, b0, inp1, nullptr);
    moe_gemm<288, 256, 2><<<dim3(4, 32, 8), blk, 0, stream>>>(inp1, Wt1, cf, partial);
    moe_finish<256, 256, true, 8><<<dim3(256), blk, 0, stream>>>(partial, cf, b1, inp2, nullptr);
    moe_gemm<288, 192, 2><<<dim3(3, 32, 8), blk, 0, stream>>>(inp2, Wt2, cf, partial);
    moe_finish<192, 171, false, 8><<<dim3(256), blk, 0, stream>>>(partial, cf, b2, nullptr, out_layer);
}